// Round 9
// baseline (1601.735 us; speedup 1.0000x reference)
//
#include <hip/hip_runtime.h>
#include <hip/hip_fp16.h>

typedef _Float16 half8 __attribute__((ext_vector_type(8)));
typedef float floatx4 __attribute__((ext_vector_type(4)));

// ---------------- degree count (deg starts memset-0; +1 self-loop folded later) ----
__global__ __launch_bounds__(256) void deg_count_k(const int* __restrict__ col, int e,
                                                   int* __restrict__ deg) {
    int i = blockIdx.x * 256 + threadIdx.x;
    if (i < e) atomicAdd(&deg[col[i]], 1);
}

// ---------------- weight convert + transpose: Wt[n][k] = (half)W[k][n] ----------
__global__ __launch_bounds__(256) void wconv_k(const float* __restrict__ W1,
                                               const float* __restrict__ W2,
                                               const float* __restrict__ W3,
                                               __half* __restrict__ Wt1,
                                               __half* __restrict__ Wt2,
                                               __half* __restrict__ Wt3) {
    int idx = blockIdx.x * 256 + threadIdx.x;
    if (idx < 16384) {
        int k = idx >> 7, nn = idx & 127;
        Wt1[nn * 128 + k] = __float2half(W1[idx]);
    } else if (idx < 32768) {
        int j = idx - 16384;
        int k = j >> 7, nn = j & 127;
        Wt2[nn * 128 + k] = __float2half(W2[j]);
    } else if (idx < 40960) {
        int j = idx - 32768;
        int k = j >> 6, nn = j & 63;
        Wt3[nn * 128 + k] = __float2half(W3[j]);
    }
}

// ---------------- 3-phase exclusive scan of (deg+1) -> col_ptr, cur, dinv ---------
__global__ __launch_bounds__(256) void scan_p1(const int* __restrict__ deg, int n,
                                               int* __restrict__ bsum) {
    __shared__ int lds[256];
    int t = threadIdx.x;
    int base = blockIdx.x * 1024 + t * 4;
    int s = 0;
#pragma unroll
    for (int i = 0; i < 4; i++) {
        int idx = base + i;
        if (idx < n) s += deg[idx] + 1;
    }
    lds[t] = s;
    __syncthreads();
    for (int o = 128; o > 0; o >>= 1) {
        if (t < o) lds[t] += lds[t + o];
        __syncthreads();
    }
    if (t == 0) bsum[blockIdx.x] = lds[0];
}

__global__ __launch_bounds__(256) void scan_p2(int* __restrict__ bsum, int nb) {
    __shared__ int lds[256];
    int t = threadIdx.x;
    int v = (t < nb) ? bsum[t] : 0;
    lds[t] = v;
    __syncthreads();
    for (int o = 1; o < 256; o <<= 1) {
        int tmp = 0;
        if (t >= o) tmp = lds[t - o];
        __syncthreads();
        lds[t] += tmp;
        __syncthreads();
    }
    if (t < nb) bsum[t] = lds[t] - v;  // exclusive
}

__global__ __launch_bounds__(256) void scan_p3(const int* __restrict__ deg, int n,
                                               const int* __restrict__ bsum,
                                               int* __restrict__ cptr,
                                               int* __restrict__ cur,
                                               float* __restrict__ dinv) {
    __shared__ int lds[256];
    int t = threadIdx.x;
    int base = blockIdx.x * 1024 + t * 4;
    int v[4];
    int s = 0;
#pragma unroll
    for (int i = 0; i < 4; i++) {
        int idx = base + i;
        v[i] = (idx < n) ? deg[idx] + 1 : 0;
        s += v[i];
    }
    lds[t] = s;
    __syncthreads();
    for (int o = 1; o < 256; o <<= 1) {
        int tmp = 0;
        if (t >= o) tmp = lds[t - o];
        __syncthreads();
        lds[t] += tmp;
        __syncthreads();
    }
    int off = bsum[blockIdx.x] + (lds[t] - s);
#pragma unroll
    for (int i = 0; i < 4; i++) {
        int idx = base + i;
        if (idx < n) {
            cptr[idx] = off;
            cur[idx] = off;
            dinv[idx] = rsqrtf((float)v[i]);
            off += v[i];
            if (idx == n - 1) cptr[n] = off;
        }
    }
}

// ---------------- bucket fill: window-owned counting-sort scatter ----------------
// NW=8 dst-windows (meta window ~850KB, L2-resident) x BPW=4 writer blocks each.
// Writers-per-meta-line <= 4 -> bounded write-back duplication; each block scans a
// contiguous quarter of the edge list (coalesced; L3 absorbs the 8x re-read).
#define FW_NW 8
#define FW_BPW 4
__global__ __launch_bounds__(256) void fill_k(const int* __restrict__ row,
                                              const int* __restrict__ col, int E, int N,
                                              int* __restrict__ cur,
                                              int* __restrict__ meta) {
    int w = blockIdx.x / FW_BPW;  // window id
    int p = blockIdx.x % FW_BPW;  // part id
    int chunk = (N + FW_NW - 1) / FW_NW;
    int dlo = w * chunk;
    int dhi = min(N, dlo + chunk);
    int total = E + N;
    int Q = (total + FW_BPW - 1) / FW_BPW;
    int ihi = min(total, p * Q + Q);
    for (int i = p * Q + threadIdx.x; i < ihi; i += 256) {
        int s, d;
        if (i < E) {
            s = row[i];
            d = col[i];
        } else {
            s = d = i - E;  // self-loop
        }
        if (d >= dlo && d < dhi) {
            int pos = atomicAdd(&cur[d], 1);
            meta[pos] = s;
        }
    }
}

// ---------------- f16 MFMA GEMM: C[n][DOUT] = (half)(dinv[r] * A[n][128] @ W) ------
template <typename AT, int DOUT>
__global__ __launch_bounds__(256) void gemm_mfma(const AT* __restrict__ A,
                                                 const __half* __restrict__ Wt,
                                                 const float* __restrict__ dinv,
                                                 __half* __restrict__ C, int n) {
    constexpr int CT = DOUT / 16;  // col tiles: 8 or 4
    constexpr int WP = 136;        // padded LDS stride (halves)
    __shared__ _Float16 ldsW[DOUT * WP];
    int tid = threadIdx.x;
    int lane = tid & 63;
    int wid = tid >> 6;
    for (int i = tid; i < DOUT * 16; i += 256) {
        int nrow = i >> 4;
        int kc = (i & 15) * 8;
        *(half8*)(&ldsW[nrow * WP + kc]) =
            *(const half8*)((const _Float16*)Wt + nrow * 128 + kc);
    }
    __syncthreads();
    int rwb = blockIdx.x * 128 + wid * 32;
    int m = lane & 15;
    int quad = lane >> 4;
    floatx4 acc[2][CT];
#pragma unroll
    for (int t = 0; t < 2; t++)
#pragma unroll
        for (int c = 0; c < CT; c++) acc[t][c] = (floatx4){0.f, 0.f, 0.f, 0.f};

#pragma unroll
    for (int kq = 0; kq < 4; kq++) {
        int k0 = kq * 32 + quad * 8;
        half8 afr[2];
#pragma unroll
        for (int t = 0; t < 2; t++) {
            int r = rwb + t * 16 + m;
            r = r < n ? r : n - 1;  // clamp (results unused for OOB rows)
            const AT* ap = A + (size_t)r * 128 + k0;
            if constexpr (sizeof(AT) == 2) {
                afr[t] = *(const half8*)ap;
            } else {
                float4 f0 = *(const float4*)ap;
                float4 f1 = *(const float4*)(ap + 4);
                half8 h;
                h[0] = (_Float16)f0.x; h[1] = (_Float16)f0.y;
                h[2] = (_Float16)f0.z; h[3] = (_Float16)f0.w;
                h[4] = (_Float16)f1.x; h[5] = (_Float16)f1.y;
                h[6] = (_Float16)f1.z; h[7] = (_Float16)f1.w;
                afr[t] = h;
            }
        }
#pragma unroll
        for (int c = 0; c < CT; c++) {
            half8 bfr = *(const half8*)(&ldsW[(c * 16 + m) * WP + k0]);
#pragma unroll
            for (int t = 0; t < 2; t++)
                acc[t][c] =
                    __builtin_amdgcn_mfma_f32_16x16x32_f16(afr[t], bfr, acc[t][c], 0, 0, 0);
        }
    }
#pragma unroll
    for (int t = 0; t < 2; t++) {
#pragma unroll
        for (int reg = 0; reg < 4; reg++) {
            int r = rwb + t * 16 + quad * 4 + reg;
            if (r < n) {
                float dv = dinv[r];
#pragma unroll
                for (int c = 0; c < CT; c++)
                    C[(size_t)r * DOUT + c * 16 + m] = __float2half(acc[t][c][reg] * dv);
            }
        }
    }
}

// ---------------- gather-aggregate: out[d] = dinv[d] * sum xw[src] + bias ----------
template <int D, bool RELU, typename OT>
__global__ __launch_bounds__(256) void aggregate_k(const __half* __restrict__ xw,
                                                   const int* __restrict__ ptr,
                                                   const int* __restrict__ meta,
                                                   const float* __restrict__ bias,
                                                   const float* __restrict__ dinv,
                                                   OT* __restrict__ out, int n) {
    constexpr int GS = D / 8;    // lanes per row (16 or 8)
    constexpr int EPW = 64 / GS; // edges per wave-load (4 or 8)
    __shared__ int smeta[4][64];
    int lane = threadIdx.x & 63;
    int wid = threadIdx.x >> 6;
    int node = blockIdx.x * 4 + wid;
    if (node >= n) return;
    int e0 = ptr[node], e1 = ptr[node + 1];
    float dv = dinv[node];
    int sub = lane / GS;   // edge sub-slot
    int cg = lane % GS;    // column group
    const _Float16* xp = (const _Float16*)xw + cg * 8;
    float acc[8];
#pragma unroll
    for (int i = 0; i < 8; i++) acc[i] = 0.f;

    for (int base = e0; base < e1; base += 64) {
        int cnt = min(e1 - base, 64);
        if (lane < cnt) smeta[wid][lane] = meta[base + lane];
        for (int j = 0; j < cnt; j += EPW) {
            int e = j + sub;
            bool valid = e < cnt;
            int s = smeta[wid][valid ? e : 0];
            half8 v = *(const half8*)(xp + (size_t)s * D);
            float msk = valid ? 1.f : 0.f;
#pragma unroll
            for (int i = 0; i < 8; i++) acc[i] = fmaf(msk, (float)v[i], acc[i]);
        }
    }
#pragma unroll
    for (int off = GS; off < 64; off <<= 1) {
#pragma unroll
        for (int i = 0; i < 8; i++) acc[i] += __shfl_xor(acc[i], off, 64);
    }
    if (lane < GS) {
        float4 bb0 = *(const float4*)(bias + cg * 8);
        float4 bb1 = *(const float4*)(bias + cg * 8 + 4);
        float r[8];
        r[0] = acc[0] * dv + bb0.x; r[1] = acc[1] * dv + bb0.y;
        r[2] = acc[2] * dv + bb0.z; r[3] = acc[3] * dv + bb0.w;
        r[4] = acc[4] * dv + bb1.x; r[5] = acc[5] * dv + bb1.y;
        r[6] = acc[6] * dv + bb1.z; r[7] = acc[7] * dv + bb1.w;
        if (RELU) {
#pragma unroll
            for (int i = 0; i < 8; i++) r[i] = fmaxf(r[i], 0.f);
        }
        if constexpr (sizeof(OT) == 2) {
            half8 h;
#pragma unroll
            for (int i = 0; i < 8; i++) h[i] = (_Float16)r[i];
            *(half8*)((_Float16*)out + (size_t)node * D + cg * 8) = h;
        } else {
            float* op = (float*)out + (size_t)node * D + cg * 8;
            *(float4*)op = make_float4(r[0], r[1], r[2], r[3]);
            *(float4*)(op + 4) = make_float4(r[4], r[5], r[6], r[7]);
        }
    }
}

extern "C" void kernel_launch(void* const* d_in, const int* in_sizes, int n_in,
                              void* d_out, int out_size, void* d_ws, size_t ws_size,
                              hipStream_t stream) {
    const float* x = (const float*)d_in[0];
    const int* ei = (const int*)d_in[1];
    const float* W1 = (const float*)d_in[2];
    const float* b1 = (const float*)d_in[3];
    const float* W2 = (const float*)d_in[4];
    const float* b2 = (const float*)d_in[5];
    const float* W3 = (const float*)d_in[6];
    const float* b3 = (const float*)d_in[7];
    float* out = (float*)d_out;
    int N = in_sizes[0] / 128;
    int E = in_sizes[1] / 2;
    const int* row = ei;
    const int* col = ei + E;
    int T = E + N;

    char* w = (char*)d_ws;
    size_t off = 0;
    auto alloc = [&](size_t bytes) -> void* {
        void* p = w + off;
        off = (off + bytes + 511) & ~(size_t)511;
        return p;
    };
    __half* bufH = (__half*)alloc((size_t)N * 128 * 2);   // xw (dinv-scaled, fp16)
    __half* bufA = (__half*)alloc((size_t)N * 128 * 2);   // hidden h (fp16 GEMM input)
    __half* Wt1 = (__half*)alloc(16384 * 2);
    __half* Wt2 = (__half*)alloc(16384 * 2);
    __half* Wt3 = (__half*)alloc(8192 * 2);
    int* deg = (int*)alloc((size_t)N * 4);
    float* dinv = (float*)alloc((size_t)N * 4);
    int* cptr = (int*)alloc((size_t)(N + 1) * 4);
    int* cur = (int*)alloc((size_t)N * 4);
    int* meta = (int*)alloc((size_t)T * 4);
    int* bsum = (int*)alloc(4096);

    int nb = (N + 1023) / 1024;
    wconv_k<<<160, 256, 0, stream>>>(W1, W2, W3, Wt1, Wt2, Wt3);
    hipMemsetAsync(deg, 0, (size_t)N * 4, stream);
    deg_count_k<<<(E + 255) / 256, 256, 0, stream>>>(col, E, deg);
    scan_p1<<<nb, 256, 0, stream>>>(deg, N, bsum);
    scan_p2<<<1, 256, 0, stream>>>(bsum, nb);
    scan_p3<<<nb, 256, 0, stream>>>(deg, N, bsum, cptr, cur, dinv);
    fill_k<<<FW_NW * FW_BPW, 256, 0, stream>>>(row, col, E, N, cur, meta);

    int gb = (N + 127) / 128;
    int ab = (N + 3) / 4;
    gemm_mfma<float, 128><<<gb, 256, 0, stream>>>(x, Wt1, dinv, bufH, N);
    aggregate_k<128, true, __half><<<ab, 256, 0, stream>>>(bufH, cptr, meta, b1, dinv, bufA, N);
    gemm_mfma<__half, 128><<<gb, 256, 0, stream>>>(bufA, Wt2, dinv, bufH, N);
    aggregate_k<128, true, __half><<<ab, 256, 0, stream>>>(bufH, cptr, meta, b2, dinv, bufA, N);
    gemm_mfma<__half, 64><<<gb, 256, 0, stream>>>(bufA, Wt3, dinv, bufH, N);
    aggregate_k<64, false, float><<<ab, 256, 0, stream>>>(bufH, cptr, meta, b3, dinv, out, N);
}

// Round 10
// 462.213 us; speedup vs baseline: 3.4654x; 3.4654x over previous
//
#include <hip/hip_runtime.h>
#include <hip/hip_fp16.h>

typedef _Float16 half8 __attribute__((ext_vector_type(8)));
typedef float floatx4 __attribute__((ext_vector_type(4)));

// ---------------- degree count (deg starts memset-0; +1 self-loop folded in scan) --
__global__ __launch_bounds__(256) void deg_count_k(const int* __restrict__ col, int e,
                                                   int* __restrict__ deg) {
    int stride = gridDim.x * 256;
    for (int i = blockIdx.x * 256 + threadIdx.x; i < e; i += stride) {
        int d = __builtin_nontemporal_load(col + i);
        atomicAdd(&deg[d], 1);
    }
}

// ---------------- weight convert + transpose: Wt[n][k] = (half)W[k][n] ----------
__global__ __launch_bounds__(256) void wconv_k(const float* __restrict__ W1,
                                               const float* __restrict__ W2,
                                               const float* __restrict__ W3,
                                               __half* __restrict__ Wt1,
                                               __half* __restrict__ Wt2,
                                               __half* __restrict__ Wt3) {
    int idx = blockIdx.x * 256 + threadIdx.x;
    if (idx < 16384) {
        int k = idx >> 7, nn = idx & 127;
        Wt1[nn * 128 + k] = __float2half(W1[idx]);
    } else if (idx < 32768) {
        int j = idx - 16384;
        int k = j >> 7, nn = j & 127;
        Wt2[nn * 128 + k] = __float2half(W2[j]);
    } else if (idx < 40960) {
        int j = idx - 32768;
        int k = j >> 6, nn = j & 63;
        Wt3[nn * 128 + k] = __float2half(W3[j]);
    }
}

// ---------------- 3-phase exclusive scan of (deg+1) -> col_ptr, cur, dinv ---------
__global__ __launch_bounds__(256) void scan_p1(const int* __restrict__ deg, int n,
                                               int* __restrict__ bsum) {
    __shared__ int lds[256];
    int t = threadIdx.x;
    int base = blockIdx.x * 1024 + t * 4;
    int s = 0;
#pragma unroll
    for (int i = 0; i < 4; i++) {
        int idx = base + i;
        if (idx < n) s += deg[idx] + 1;
    }
    lds[t] = s;
    __syncthreads();
    for (int o = 128; o > 0; o >>= 1) {
        if (t < o) lds[t] += lds[t + o];
        __syncthreads();
    }
    if (t == 0) bsum[blockIdx.x] = lds[0];
}

__global__ __launch_bounds__(256) void scan_p2(int* __restrict__ bsum, int nb) {
    __shared__ int lds[256];
    int t = threadIdx.x;
    int v = (t < nb) ? bsum[t] : 0;
    lds[t] = v;
    __syncthreads();
    for (int o = 1; o < 256; o <<= 1) {
        int tmp = 0;
        if (t >= o) tmp = lds[t - o];
        __syncthreads();
        lds[t] += tmp;
        __syncthreads();
    }
    if (t < nb) bsum[t] = lds[t] - v;  // exclusive
}

__global__ __launch_bounds__(256) void scan_p3(const int* __restrict__ deg, int n,
                                               const int* __restrict__ bsum,
                                               int* __restrict__ cptr,
                                               int* __restrict__ cur,
                                               float* __restrict__ dinv) {
    __shared__ int lds[256];
    int t = threadIdx.x;
    int base = blockIdx.x * 1024 + t * 4;
    int v[4];
    int s = 0;
#pragma unroll
    for (int i = 0; i < 4; i++) {
        int idx = base + i;
        v[i] = (idx < n) ? deg[idx] + 1 : 0;
        s += v[i];
    }
    lds[t] = s;
    __syncthreads();
    for (int o = 1; o < 256; o <<= 1) {
        int tmp = 0;
        if (t >= o) tmp = lds[t - o];
        __syncthreads();
        lds[t] += tmp;
        __syncthreads();
    }
    int off = bsum[blockIdx.x] + (lds[t] - s);
#pragma unroll
    for (int i = 0; i < 4; i++) {
        int idx = base + i;
        if (idx < n) {
            cptr[idx] = off;
            cur[idx] = off;
            dinv[idx] = rsqrtf((float)v[i]);
            off += v[i];
            if (idx == n - 1) cptr[n] = off;
        }
    }
}

// ---------------- bucket fill: XCD-chunked scatter, NT edge-list reads ----------
// 8 dst-range chunks; team k = blocks with blockIdx&7==k (round-robin -> same XCD).
// Each team grid-strides the full edge list with NON-TEMPORAL loads so the 13.6MB
// stream doesn't evict the team's ~850KB L2-resident meta window mid-fill.
__global__ __launch_bounds__(256) void fill_k(const int* __restrict__ row,
                                              const int* __restrict__ col, int E, int N,
                                              int* __restrict__ cur,
                                              int* __restrict__ meta) {
    int chunkid = blockIdx.x & 7;
    int team = blockIdx.x >> 3;
    int nteams = gridDim.x >> 3;
    int chunk = (N + 7) >> 3;
    int dlo = chunkid * chunk;
    int dhi = min(N, dlo + chunk);
    int total = E + N;
    for (int i = team * 256 + threadIdx.x; i < total; i += nteams * 256) {
        int s, d;
        if (i < E) {
            s = __builtin_nontemporal_load(row + i);
            d = __builtin_nontemporal_load(col + i);
        } else {
            s = d = i - E;  // self-loop
        }
        if (d >= dlo && d < dhi) {
            int p = atomicAdd(&cur[d], 1);
            meta[p] = s;
        }
    }
}

// ---------------- f16 MFMA GEMM: C[n][DOUT] = (half)(dinv[r] * A[n][128] @ W) ------
template <typename AT, int DOUT>
__global__ __launch_bounds__(256) void gemm_mfma(const AT* __restrict__ A,
                                                 const __half* __restrict__ Wt,
                                                 const float* __restrict__ dinv,
                                                 __half* __restrict__ C, int n) {
    constexpr int CT = DOUT / 16;  // col tiles: 8 or 4
    constexpr int WP = 136;        // padded LDS stride (halves)
    __shared__ _Float16 ldsW[DOUT * WP];
    int tid = threadIdx.x;
    int lane = tid & 63;
    int wid = tid >> 6;
    for (int i = tid; i < DOUT * 16; i += 256) {
        int nrow = i >> 4;
        int kc = (i & 15) * 8;
        *(half8*)(&ldsW[nrow * WP + kc]) =
            *(const half8*)((const _Float16*)Wt + nrow * 128 + kc);
    }
    __syncthreads();
    int rwb = blockIdx.x * 128 + wid * 32;
    int m = lane & 15;
    int quad = lane >> 4;
    floatx4 acc[2][CT];
#pragma unroll
    for (int t = 0; t < 2; t++)
#pragma unroll
        for (int c = 0; c < CT; c++) acc[t][c] = (floatx4){0.f, 0.f, 0.f, 0.f};

#pragma unroll
    for (int kq = 0; kq < 4; kq++) {
        int k0 = kq * 32 + quad * 8;
        half8 afr[2];
#pragma unroll
        for (int t = 0; t < 2; t++) {
            int r = rwb + t * 16 + m;
            r = r < n ? r : n - 1;  // clamp (results unused for OOB rows)
            const AT* ap = A + (size_t)r * 128 + k0;
            if constexpr (sizeof(AT) == 2) {
                afr[t] = *(const half8*)ap;
            } else {
                float4 f0 = *(const float4*)ap;
                float4 f1 = *(const float4*)(ap + 4);
                half8 h;
                h[0] = (_Float16)f0.x; h[1] = (_Float16)f0.y;
                h[2] = (_Float16)f0.z; h[3] = (_Float16)f0.w;
                h[4] = (_Float16)f1.x; h[5] = (_Float16)f1.y;
                h[6] = (_Float16)f1.z; h[7] = (_Float16)f1.w;
                afr[t] = h;
            }
        }
#pragma unroll
        for (int c = 0; c < CT; c++) {
            half8 bfr = *(const half8*)(&ldsW[(c * 16 + m) * WP + k0]);
#pragma unroll
            for (int t = 0; t < 2; t++)
                acc[t][c] =
                    __builtin_amdgcn_mfma_f32_16x16x32_f16(afr[t], bfr, acc[t][c], 0, 0, 0);
        }
    }
#pragma unroll
    for (int t = 0; t < 2; t++) {
#pragma unroll
        for (int reg = 0; reg < 4; reg++) {
            int r = rwb + t * 16 + quad * 4 + reg;
            if (r < n) {
                float dv = dinv[r];
#pragma unroll
                for (int c = 0; c < CT; c++)
                    C[(size_t)r * DOUT + c * 16 + m] = __float2half(acc[t][c][reg] * dv);
            }
        }
    }
}

// ---------------- gather-aggregate: out[d] = dinv[d] * sum xw[src] + bias ----------
template <int D, bool RELU, typename OT>
__global__ __launch_bounds__(256) void aggregate_k(const __half* __restrict__ xw,
                                                   const int* __restrict__ ptr,
                                                   const int* __restrict__ meta,
                                                   const float* __restrict__ bias,
                                                   const float* __restrict__ dinv,
                                                   OT* __restrict__ out, int n) {
    constexpr int GS = D / 8;    // lanes per row (16 or 8)
    constexpr int EPW = 64 / GS; // edges per wave-load (4 or 8)
    __shared__ int smeta[4][64];
    int lane = threadIdx.x & 63;
    int wid = threadIdx.x >> 6;
    int node = blockIdx.x * 4 + wid;
    if (node >= n) return;
    int e0 = ptr[node], e1 = ptr[node + 1];
    float dv = dinv[node];
    int sub = lane / GS;   // edge sub-slot
    int cg = lane % GS;    // column group
    const _Float16* xp = (const _Float16*)xw + cg * 8;
    float acc[8];
#pragma unroll
    for (int i = 0; i < 8; i++) acc[i] = 0.f;

    for (int base = e0; base < e1; base += 64) {
        int cnt = min(e1 - base, 64);
        if (lane < cnt) smeta[wid][lane] = meta[base + lane];
        for (int j = 0; j < cnt; j += EPW) {
            int e = j + sub;
            bool valid = e < cnt;
            int s = smeta[wid][valid ? e : 0];
            half8 v = *(const half8*)(xp + (size_t)s * D);
            float msk = valid ? 1.f : 0.f;
#pragma unroll
            for (int i = 0; i < 8; i++) acc[i] = fmaf(msk, (float)v[i], acc[i]);
        }
    }
#pragma unroll
    for (int off = GS; off < 64; off <<= 1) {
#pragma unroll
        for (int i = 0; i < 8; i++) acc[i] += __shfl_xor(acc[i], off, 64);
    }
    if (lane < GS) {
        float4 bb0 = *(const float4*)(bias + cg * 8);
        float4 bb1 = *(const float4*)(bias + cg * 8 + 4);
        float r[8];
        r[0] = acc[0] * dv + bb0.x; r[1] = acc[1] * dv + bb0.y;
        r[2] = acc[2] * dv + bb0.z; r[3] = acc[3] * dv + bb0.w;
        r[4] = acc[4] * dv + bb1.x; r[5] = acc[5] * dv + bb1.y;
        r[6] = acc[6] * dv + bb1.z; r[7] = acc[7] * dv + bb1.w;
        if (RELU) {
#pragma unroll
            for (int i = 0; i < 8; i++) r[i] = fmaxf(r[i], 0.f);
        }
        if constexpr (sizeof(OT) == 2) {
            half8 h;
#pragma unroll
            for (int i = 0; i < 8; i++) h[i] = (_Float16)r[i];
            *(half8*)((_Float16*)out + (size_t)node * D + cg * 8) = h;
        } else {
            float* op = (float*)out + (size_t)node * D + cg * 8;
            *(float4*)op = make_float4(r[0], r[1], r[2], r[3]);
            *(float4*)(op + 4) = make_float4(r[4], r[5], r[6], r[7]);
        }
    }
}

extern "C" void kernel_launch(void* const* d_in, const int* in_sizes, int n_in,
                              void* d_out, int out_size, void* d_ws, size_t ws_size,
                              hipStream_t stream) {
    const float* x = (const float*)d_in[0];
    const int* ei = (const int*)d_in[1];
    const float* W1 = (const float*)d_in[2];
    const float* b1 = (const float*)d_in[3];
    const float* W2 = (const float*)d_in[4];
    const float* b2 = (const float*)d_in[5];
    const float* W3 = (const float*)d_in[6];
    const float* b3 = (const float*)d_in[7];
    float* out = (float*)d_out;
    int N = in_sizes[0] / 128;
    int E = in_sizes[1] / 2;
    const int* row = ei;
    const int* col = ei + E;
    int T = E + N;

    char* w = (char*)d_ws;
    size_t off = 0;
    auto alloc = [&](size_t bytes) -> void* {
        void* p = w + off;
        off = (off + bytes + 511) & ~(size_t)511;
        return p;
    };
    __half* bufH = (__half*)alloc((size_t)N * 128 * 2);   // xw (dinv-scaled, fp16)
    __half* bufA = (__half*)alloc((size_t)N * 128 * 2);   // hidden h (fp16 GEMM input)
    __half* Wt1 = (__half*)alloc(16384 * 2);
    __half* Wt2 = (__half*)alloc(16384 * 2);
    __half* Wt3 = (__half*)alloc(8192 * 2);
    int* deg = (int*)alloc((size_t)N * 4);
    float* dinv = (float*)alloc((size_t)N * 4);
    int* cptr = (int*)alloc((size_t)(N + 1) * 4);
    int* cur = (int*)alloc((size_t)N * 4);
    int* meta = (int*)alloc((size_t)T * 4);
    int* bsum = (int*)alloc(4096);

    int nb = (N + 1023) / 1024;
    wconv_k<<<160, 256, 0, stream>>>(W1, W2, W3, Wt1, Wt2, Wt3);
    hipMemsetAsync(deg, 0, (size_t)N * 4, stream);
    deg_count_k<<<2048, 256, 0, stream>>>(col, E, deg);
    scan_p1<<<nb, 256, 0, stream>>>(deg, N, bsum);
    scan_p2<<<1, 256, 0, stream>>>(bsum, nb);
    scan_p3<<<nb, 256, 0, stream>>>(deg, N, bsum, cptr, cur, dinv);
    fill_k<<<8 * 256, 256, 0, stream>>>(row, col, E, N, cur, meta);

    int gb = (N + 127) / 128;
    int ab = (N + 3) / 4;
    gemm_mfma<float, 128><<<gb, 256, 0, stream>>>(x, Wt1, dinv, bufH, N);
    aggregate_k<128, true, __half><<<ab, 256, 0, stream>>>(bufH, cptr, meta, b1, dinv, bufA, N);
    gemm_mfma<__half, 128><<<gb, 256, 0, stream>>>(bufA, Wt2, dinv, bufH, N);
    aggregate_k<128, true, __half><<<ab, 256, 0, stream>>>(bufH, cptr, meta, b2, dinv, bufA, N);
    gemm_mfma<__half, 64><<<gb, 256, 0, stream>>>(bufA, Wt3, dinv, bufH, N);
    aggregate_k<64, false, float><<<ab, 256, 0, stream>>>(bufH, cptr, meta, b3, dinv, out, N);
}